// Round 9
// baseline (44.104 us; speedup 1.0000x reference)
//
#include <hip/hip_runtime.h>

typedef unsigned short ushort8v __attribute__((ext_vector_type(8)));
typedef float float4v __attribute__((ext_vector_type(4)));

namespace {
constexpr int kB = 2, kC = 256, kH = 100, kW = 152;
constexpr int kN = 1000;
constexpr int kPH = 7, kPW = 7, kSR = 2;
constexpr float kScale = 0.0625f;
constexpr int kHW = kH * kW;                 // 15200
constexpr int kWC = kW * kC;                 // NHWC row stride (elems)
constexpr int kBins = kPH * kPW;             // 49
constexpr int kOutPerRoi = kC * kBins;       // 12544
constexpr int kStrideE = 260;                // bf16 elems; 130 u32 words
constexpr int kNY = kPH * kSR;               // 14
constexpr int kNX = kPW * kSR;               // 14
constexpr int kThreads = 448;                // 7 waves, one bin-row each
}

__device__ __forceinline__ float b2f(unsigned short u) {
  union { unsigned int i; float f; } x; x.i = ((unsigned int)u) << 16; return x.f;
}
__device__ __forceinline__ unsigned short f2b(float f) {
  union { float f; unsigned int i; } x; x.f = f;
  return (unsigned short)((x.i + 0x7FFFu + ((x.i >> 16) & 1u)) >> 16);  // RNE
}

// (B,C,H,W) f32 -> (B,H*W,C) bf16, tiled 32x32 transpose
__global__ __launch_bounds__(256) void transpose_k(const float* __restrict__ in,
                                                   unsigned short* __restrict__ out) {
  __shared__ float tile[32][33];
  const int b = blockIdx.z;
  const int hw0 = blockIdx.x * 32;
  const int c0 = blockIdx.y * 32;
  const int tx = threadIdx.x;   // 0..7  (x4 floats)
  const int ty = threadIdx.y;   // 0..31
  const float4 v = *(const float4*)(in + (size_t)b * kC * kHW +
                                    (size_t)(c0 + ty) * kHW + hw0 + tx * 4);
  tile[tx * 4 + 0][ty] = v.x;
  tile[tx * 4 + 1][ty] = v.y;
  tile[tx * 4 + 2][ty] = v.z;
  tile[tx * 4 + 3][ty] = v.w;
  __syncthreads();
  unsigned int lo = (unsigned int)f2b(tile[ty][tx * 4 + 0]) |
                    ((unsigned int)f2b(tile[ty][tx * 4 + 1]) << 16);
  unsigned int hi = (unsigned int)f2b(tile[ty][tx * 4 + 2]) |
                    ((unsigned int)f2b(tile[ty][tx * 4 + 3]) << 16);
  unsigned int* dst = (unsigned int*)(out + (size_t)b * kHW * kC +
                                      (size_t)(hw0 + ty) * kC + c0 + tx * 4);
  dst[0] = lo;
  dst[1] = hi;
}

// one block per ROI; 7 waves; wave w = bin-row ph=w (7 contiguous bins):
// same y-rows all iterations (hoisted), x advances -> L1 reuse between bins.
// lanes 0-31 = x-lo column of a pair, 32-63 = x-hi; lane covers 8 channels.
__global__ __launch_bounds__(kThreads, 7) void roialign_k(
    const unsigned short* __restrict__ ft, const float* __restrict__ rois,
    float* __restrict__ out) {
  __shared__ unsigned short sOut[kBins * kStrideE];  // ~24.9 KB
  __shared__ int sYlo[kNY], sXlo[kNX];
  __shared__ float sHy[kNY], sLy[kNY], sHx[kNX], sLx[kNX];
  __shared__ int sB;

  const int n = blockIdx.x;
  const int t = threadIdx.x;

  if (t < kNY + kNX) {
    const bool isX = t >= kNY;
    const int i = isX ? t - kNY : t;
    const float x1 = rois[n * 5 + 1] * kScale;
    const float y1 = rois[n * 5 + 2] * kScale;
    const float x2 = rois[n * 5 + 3] * kScale;
    const float y2 = rois[n * 5 + 4] * kScale;
    const float roiw = fmaxf(x2 - x1, 1.0f);
    const float roih = fmaxf(y2 - y1, 1.0f);
    const float start = isX ? x1 : y1;
    const float binsz = isX ? (roiw / kPW) : (roih / kPH);
    const float size = isX ? (float)kW : (float)kH;
    const int p = i / kSR, s = i % kSR;
    const float c = start + p * binsz + (s + 0.5f) * binsz / kSR;
    const bool valid = (c > -1.0f) && (c < size);
    const float cc = fminf(fmaxf(c, 0.0f), size - 1.0f);
    const float lo = fminf(floorf(cc), size - 2.0f);
    const float fr = cc - lo;
    // fold the 1/(SR*SR)=0.25 average into the weights (0.5 per axis)
    const float wHi = valid ? (1.0f - fr) * 0.5f : 0.0f;
    const float wLo = valid ? fr * 0.5f : 0.0f;
    if (isX) { sXlo[i] = (int)lo; sHx[i] = wHi; sLx[i] = wLo; }
    else     { sYlo[i] = (int)lo; sHy[i] = wHi; sLy[i] = wLo; }
  }
  if (t == 0) sB = (int)rois[n * 5 + 0];
  __syncthreads();

  const int ph = t >> 6;         // wave id = bin row, 0..6
  const int lane = t & 63;
  const int half = lane >> 5;    // 0: x-lo column of pair, 1: x-hi
  const int sub = lane & 31;     // channel octet index
  const unsigned short* fb = ft + (size_t)sB * kHW * kC + half * kC + sub * 8;
  unsigned int* s32 = (unsigned int*)sOut;

  // hoist this row's y-state (same for all 7 bins of the wave)
  const int iy0 = ph * kSR, iy1 = iy0 + 1;
  const int rA = sYlo[iy0] * kWC;        // sample 0, top row offset
  const int rB = sYlo[iy1] * kWC;        // sample 1, top row offset
  const float hy0 = sHy[iy0], ly0 = sLy[iy0];
  const float hy1 = sHy[iy1], ly1 = sLy[iy1];

  for (int pw = 0; pw < kPW; ++pw) {
    const int bin = ph * kPW + pw;
    float acc[8] = {0.f, 0.f, 0.f, 0.f, 0.f, 0.f, 0.f, 0.f};
#pragma unroll
    for (int sx = 0; sx < kSR; ++sx) {
      const int ix = pw * kSR + sx;
      const int xo = sXlo[ix] * kC;
      const float hxs = half ? sLx[ix] : sHx[ix];   // this half's x-weight
      const ushort8v vA0 = *(const ushort8v*)(fb + rA + xo);        // s0 top
      const ushort8v vA1 = *(const ushort8v*)(fb + rA + xo + kWC);  // s0 bot
      const ushort8v vB0 = *(const ushort8v*)(fb + rB + xo);        // s1 top
      const ushort8v vB1 = *(const ushort8v*)(fb + rB + xo + kWC);  // s1 bot
      const float wA0 = hy0 * hxs, wA1 = ly0 * hxs;
      const float wB0 = hy1 * hxs, wB1 = ly1 * hxs;
#pragma unroll
      for (int k = 0; k < 8; ++k)
        acc[k] += wA0 * b2f(vA0[k]) + wA1 * b2f(vA1[k]) +
                  wB0 * b2f(vB0[k]) + wB1 * b2f(vB1[k]);
    }
    // merge the two column-halves: butterfly across lane^32
#pragma unroll
    for (int k = 0; k < 8; ++k) acc[k] += __shfl_xor(acc[k], 32);
    const int kBase = half * 4;
    const unsigned int wA = (unsigned int)f2b(acc[kBase + 0]) |
                            ((unsigned int)f2b(acc[kBase + 1]) << 16);
    const unsigned int wB = (unsigned int)f2b(acc[kBase + 2]) |
                            ((unsigned int)f2b(acc[kBase + 3]) << 16);
    const int wIdx = bin * (kStrideE / 2) + sub * 4 + half * 2;
    s32[wIdx + 0] = wA;
    s32[wIdx + 1] = wB;
  }
  __syncthreads();

  // coalesced non-temporal float4 write of this ROI's (C,PH,PW) block
  float4v* ob4 = (float4v*)(out + (size_t)n * kOutPerRoi);
  for (int q = t; q < kOutPerRoi / 4; q += kThreads) {
    const int f = q * 4;
    const int c0 = (f + 0) / kBins, b0 = (f + 0) - c0 * kBins;
    const int c1 = (f + 1) / kBins, b1 = (f + 1) - c1 * kBins;
    const int c2 = (f + 2) / kBins, b2 = (f + 2) - c2 * kBins;
    const int c3 = (f + 3) / kBins, b3 = (f + 3) - c3 * kBins;
    float4v v;
    v.x = b2f(sOut[b0 * kStrideE + c0]);
    v.y = b2f(sOut[b1 * kStrideE + c1]);
    v.z = b2f(sOut[b2 * kStrideE + c2]);
    v.w = b2f(sOut[b3 * kStrideE + c3]);
    __builtin_nontemporal_store(v, &ob4[q]);
  }
}

extern "C" void kernel_launch(void* const* d_in, const int* in_sizes, int n_in,
                              void* d_out, int out_size, void* d_ws, size_t ws_size,
                              hipStream_t stream) {
  const float* feat = (const float*)d_in[0];
  const float* rois = (const float*)d_in[1];
  float* out = (float*)d_out;
  unsigned short* ft = (unsigned short*)d_ws;  // kB*kHW*kC*2 = 15.6 MB scratch

  hipLaunchKernelGGL(transpose_k, dim3(kHW / 32, kC / 32, kB), dim3(8, 32), 0,
                     stream, feat, ft);
  hipLaunchKernelGGL(roialign_k, dim3(kN), dim3(kThreads), 0, stream, ft, rois, out);
}